// Round 1
// baseline (769.526 us; speedup 1.0000x reference)
//
#include <hip/hip_runtime.h>
#include <math.h>

#define VOCAB 32000
#define BATCH 8
#define SEQ 512
#define ROWS (BATCH * SEQ)
#define IGNORE_INDEX (-100)
#define LABEL_SMOOTH 0.1f
#define REP_WEIGHT 0.2f

// Workspace layout:
//   [0, BATCH*VOCAB) int32            : per-batch argmax histogram
//   then 3 floats                     : ce_sum, valid_cnt, rep_sum
#define COUNTS_ELEMS (BATCH * VOCAB)
#define WS_TOTAL_INTS (COUNTS_ELEMS + 3)

__global__ void zero_ws_kernel(int* __restrict__ p, int n) {
    int i = blockIdx.x * blockDim.x + threadIdx.x;
    if (i < n) p[i] = 0;
}

// One block per (b,s) row: online softmax + sum + argmax in a single pass.
__global__ __launch_bounds__(256) void row_kernel(
    const float* __restrict__ logits,
    const int* __restrict__ labels,
    int* __restrict__ counts,
    float* __restrict__ accums) {

    const int row = blockIdx.x;
    const int tid = threadIdx.x;
    const float4* rowp = (const float4*)(logits + (size_t)row * VOCAB);

    float m = -INFINITY;   // running max
    float l = 0.0f;        // running sum of exp(x - m)
    float s = 0.0f;        // running sum of x
    int   mi = 0;          // argmax index (first occurrence)

    for (int i = tid; i < VOCAB / 4; i += 256) {
        float4 x = rowp[i];
        float vals[4] = {x.x, x.y, x.z, x.w};
        #pragma unroll
        for (int j = 0; j < 4; ++j) {
            float v = vals[j];
            s += v;
            if (v > m) {
                l = l * __expf(m - v) + 1.0f;
                m = v;
                mi = i * 4 + j;
            } else {
                l += __expf(v - m);
            }
        }
    }

    __shared__ float sm[256], sl[256], ss[256];
    __shared__ int   si[256];
    sm[tid] = m; sl[tid] = l; ss[tid] = s; si[tid] = mi;
    __syncthreads();

    for (int off = 128; off > 0; off >>= 1) {
        if (tid < off) {
            float m1 = sm[tid], l1 = sl[tid];
            float m2 = sm[tid + off], l2 = sl[tid + off];
            float mm = fmaxf(m1, m2);
            sl[tid] = l1 * __expf(m1 - mm) + l2 * __expf(m2 - mm);
            sm[tid] = mm;
            ss[tid] += ss[tid + off];
            int i1 = si[tid], i2 = si[tid + off];
            if (m2 > m1 || (m2 == m1 && i2 < i1)) si[tid] = i2;
        }
        __syncthreads();
    }

    if (tid == 0) {
        float lse = sm[0] + logf(sl[0]);
        float mean_logits = ss[0] * (1.0f / (float)VOCAB);
        int label = labels[row];
        bool valid = (label != IGNORE_INDEX);
        int safe = valid ? label : 0;
        float logit_lab = logits[(size_t)row * VOCAB + safe];
        float nll = lse - logit_lab;           // -logp[label]
        float smooth = lse - mean_logits;      // -mean(logp)
        float per_tok = (1.0f - LABEL_SMOOTH) * nll + LABEL_SMOOTH * smooth;
        if (valid) {
            atomicAdd(&accums[0], per_tok);    // ce numerator
            atomicAdd(&accums[1], 1.0f);       // valid count
            atomicAdd(&counts[(row / SEQ) * VOCAB + si[0]], 1);
        }
    }
}

// One block per batch row: histogram -> entropy-based repetition score.
__global__ __launch_bounds__(256) void rep_kernel(
    const int* __restrict__ counts, float* __restrict__ accums) {

    const int b = blockIdx.x;
    const int tid = threadIdx.x;
    const int* c = counts + b * VOCAB;

    __shared__ float sf[256];
    __shared__ int   sn[256];

    // pass 1: total count
    int tot = 0;
    for (int i = tid; i < VOCAB; i += 256) tot += c[i];
    sn[tid] = tot;
    __syncthreads();
    for (int off = 128; off > 0; off >>= 1) {
        if (tid < off) sn[tid] += sn[tid + off];
        __syncthreads();
    }
    const int total_i = sn[0];
    __syncthreads();
    const float total = fmaxf((float)total_i, 1.0f);

    // pass 2: entropy (exact reference formula) + n_unique
    float ent = 0.0f;
    int nu = 0;
    for (int i = tid; i < VOCAB; i += 256) {
        int cv = c[i];
        if (cv > 0) {
            float p = (float)cv / total;
            ent -= p * logf(p + 1e-10f);
            nu++;
        }
    }
    sf[tid] = ent; sn[tid] = nu;
    __syncthreads();
    for (int off = 128; off > 0; off >>= 1) {
        if (tid < off) { sf[tid] += sf[tid + off]; sn[tid] += sn[tid + off]; }
        __syncthreads();
    }

    if (tid == 0) {
        float per_b = 0.0f;
        if (total_i > 0) {
            float max_entropy = logf((float)sn[0] + 1.0f);
            per_b = 1.0f - sf[0] / max_entropy;
        }
        atomicAdd(&accums[2], per_b);
    }
}

__global__ void finalize_kernel(const float* __restrict__ accums,
                                float* __restrict__ out) {
    float ce = accums[0] / fmaxf(accums[1], 1.0f);
    float rep = accums[2] * (1.0f / (float)BATCH);
    out[0] = ce + REP_WEIGHT * rep;
    out[1] = ce;
    out[2] = rep;
}

extern "C" void kernel_launch(void* const* d_in, const int* in_sizes, int n_in,
                              void* d_out, int out_size, void* d_ws, size_t ws_size,
                              hipStream_t stream) {
    const float* logits = (const float*)d_in[0];
    const int* labels = (const int*)d_in[1];
    // d_in[2] = input_ids, unused by the loss math (only gates rep != 0)

    int* counts = (int*)d_ws;
    float* accums = (float*)((char*)d_ws + (size_t)COUNTS_ELEMS * sizeof(int));
    float* out = (float*)d_out;

    zero_ws_kernel<<<(WS_TOTAL_INTS + 255) / 256, 256, 0, stream>>>((int*)d_ws, WS_TOTAL_INTS);
    row_kernel<<<ROWS, 256, 0, stream>>>(logits, labels, counts, accums);
    rep_kernel<<<BATCH, 256, 0, stream>>>(counts, accums);
    finalize_kernel<<<1, 1, 0, stream>>>(accums, out);
}